// Round 7
// baseline (160.251 us; speedup 1.0000x reference)
//
#include <hip/hip_runtime.h>
#include <math.h>

#define NQ 12
#define NTHREADS 512
#define NL 3

typedef _Float16 h8 __attribute__((ext_vector_type(8)));
typedef _Float16 h4 __attribute__((ext_vector_type(4)));
typedef float f4 __attribute__((ext_vector_type(4)));

// suffix-xor = CNOT-chain permutation (R4-verified convention)
__device__ __forceinline__ int sfx(int v) {
    v ^= v >> 1; v ^= v >> 2; v ^= v >> 4; v ^= v >> 8;
    return v;
}

// State-buffer swizzle (f16 element offsets), R6-verified: flips chunk bits
// [5:3] with bits [8:6]^[11:9]; all state access patterns <=2-way (free).
__device__ __forceinline__ int swzf(int off) {
    return off ^ (((((off >> 6) ^ (off >> 9)) & 7)) << 3);
}

// W-buffer swizzle (R7): the B-fragment read off = s*1024 + u*32 + q*8 was
// 8-way conflicted unswizzled (bank quads {0,4} only). phys[5:3] =
// (u0<<2|q) ^ u[3:1] -> exact 2-way. Write side uses the same function.
__device__ __forceinline__ int swzw(int off) {
    return off ^ (((off >> 6) & 7) << 3);
}

// State layouts (step g, state index i, 8-bit row m, 4-bit t-bits, reim):
//   off_g = m*32 + reim*16 + t
//   g=0: t = i[3:0]  (wires 8..11),  m = i>>4
//   g=1: t = i[7:4]  (wires 4..7),   m = i[9:8] | i[3:0]<<2 | i[11:10]<<6
//   g=2: t = i[11:8] (wires 0..3),   m = i[7:0]
// Row-orderings chosen so a lane's 4 D-rows land contiguously in the NEXT
// layout -> b64 stores.

__global__ void __launch_bounds__(NTHREADS)
qsim_kernel(const float* __restrict__ x,
            const float* __restrict__ params,
            const float* __restrict__ head_w,
            const float* __restrict__ head_b,
            float* __restrict__ out) {
    __shared__ __align__(16) _Float16 Sst[8192];   // 16 KB state (256 x 32 f16)
    __shared__ __align__(16) _Float16 Wl[9216];    // 18 KB group matrices
    __shared__ float Gs[36 * 8];                   // 1.125 KB fused 2x2 gates
    __shared__ float wlo[64], whi[64];
    __shared__ float csx[NQ], snx[NQ];
    __shared__ float wred[NTHREADS / 64];

    const int t = threadIdx.x, b = blockIdx.x;

    // ---- Phase 1 (waves work in parallel on disjoint lanes) ----
    if (t < 36) {                    // wave 0: fused 2x2 gates G=RY(p2)RZ(p1)RY(p0)
        float p0 = params[t * 3 + 0];
        float p1 = params[t * 3 + 1];
        float p2 = params[t * 3 + 2];
        float c0 = cosf(0.5f * p0), s0 = sinf(0.5f * p0);
        float ch = cosf(0.5f * p1), sh = sinf(0.5f * p1);
        float c2 = cosf(0.5f * p2), s2 = sinf(0.5f * p2);
        float pr = ch, pi = -sh;   // p = exp(-i p1/2)
        float qr = ch, qi = sh;    // q = conj(p)
        float A = c2 * c0, Bc = s2 * s0, Cc = c2 * s0, D = s2 * c0;
        float* g = &Gs[t * 8];
        g[0] = A * pr - Bc * qr;  g[1] = A * pi - Bc * qi;   // g00
        g[2] = -Cc * pr - D * qr; g[3] = -Cc * pi - D * qi;  // g01
        g[4] = D * pr + Cc * qr;  g[5] = D * pi + Cc * qi;   // g10
        g[6] = -Bc * pr + A * qr; g[7] = -Bc * pi + A * qi;  // g11
    }
    if (t >= 64 && t < 64 + NQ) {    // wave 1: RX trig
        int i = t - 64;
        float xv = 0.5f * x[b * NQ + i];
        csx[i] = cosf(xv);
        snx[i] = sinf(xv);
    }
    if (t >= 128 && t < 192) {       // wave 2: wsum low LUT (bits 0..5 <-> wires 11..6)
        int v = t - 128; float s = 0.f;
#pragma unroll
        for (int be = 0; be < 6; ++be)
            s += ((v >> be) & 1) ? -head_w[11 - be] : head_w[11 - be];
        wlo[v] = s;
    }
    if (t >= 192 && t < 256) {       // wave 3: wsum high LUT (bits 6..11 <-> wires 5..0)
        int v = t - 192; float s = 0.f;
#pragma unroll
        for (int be = 0; be < 6; ++be)
            s += ((v >> be) & 1) ? -head_w[5 - be] : head_w[5 - be];
        whi[v] = s;
    }
    __syncthreads();

    // ---- Phase 2a: build the 9 group matrices W (32x32 f16 each) in LDS ----
    // W[s][n][k]: U[t'][t] = prod_j G[wire 11-(4g+j)][t'_j][t_j] (complex 16x16),
    // blocks [[Ur,-Ui],[Ui,Ur]]; stored k-contiguous (B-operand order), swizzled.
#pragma unroll
    for (int i = 0; i < 18; ++i) {   // 18 x 512 = 9216 elements
        int e = i * 512 + t;
        int s = e >> 10, idx = e & 1023;
        int n = idx >> 5, k = idx & 31;
        int rp = n >> 4, tp = n & 15, rr = k >> 4, tt = k & 15;
        int l = s / 3, g = s - 3 * l;
        float ur = 1.f, ui = 0.f;
#pragma unroll
        for (int jj = 0; jj < 4; ++jj) {
            int wire = 11 - (4 * g + jj);          // bit jj of t <-> wire 11-(4g+jj)
            const float* gp = &Gs[(l * 12 + wire) * 8];
            int rb = (tp >> jj) & 1, cb = (tt >> jj) & 1;
            float gr = gp[(rb * 2 + cb) * 2], gi = gp[(rb * 2 + cb) * 2 + 1];
            float nr = ur * gr - ui * gi;
            float ni = ur * gi + ui * gr;
            ur = nr; ui = ni;
        }
        float val = (rp == 0) ? ((rr == 0) ? ur : -ui)
                              : ((rr == 0) ? ui : ur);
        Wl[swzw(e)] = (_Float16)val;
    }

    // ---- Phase 2b: init product state (RX encoding), L_0 layout ----
    // amp(i) = (-i)^popc(i) * prod_w (bit_{11-w}(i) ? sin : cos)(x_w/2)
    {
        int m = t & 255, reim = t >> 8;
        float magm = 1.f;
#pragma unroll
        for (int j = 0; j < 8; ++j)       // m bit j = state bit 4+j = wire 7-j
            magm *= ((m >> j) & 1) ? snx[7 - j] : csx[7 - j];
        float A2[4], B2[4];
#pragma unroll
        for (int v = 0; v < 4; ++v) {     // t bits 0,1 = wires 11,10; bits 2,3 = wires 9,8
            A2[v] = ((v & 1) ? snx[11] : csx[11]) * ((v & 2) ? snx[10] : csx[10]);
            B2[v] = ((v & 1) ? snx[9] : csx[9]) * ((v & 2) ? snx[8] : csx[8]);
        }
        int pm = __popc(m);
        h8 w0, w1;
#pragma unroll
        for (int tau = 0; tau < 16; ++tau) {
            float mag = magm * A2[tau & 3] * B2[tau >> 2];
            int p = (pm + __popc(tau)) & 3;
            bool nz = ((p & 1) == reim);
            bool neg = ((((p >> 1) & 1) ^ reim) != 0);
            float v = nz ? (neg ? -mag : mag) : 0.f;
            if (tau < 8) w0[tau] = (_Float16)v; else w1[tau - 8] = (_Float16)v;
        }
        int off = m * 32 + reim * 16;
        *(h8*)&Sst[swzf(off)] = w0;
        *(h8*)&Sst[swzf(off + 8)] = w1;
    }
    __syncthreads();

    const int u = t & 15;          // MFMA row/col lane id
    const int q = (t >> 4) & 3;    // MFMA quad
    const int wv = t >> 6;         // wave id (0..7); tiles wv and wv+8
    const int abase0 = swzf((wv * 16 + u) * 32 + q * 8);
    const int abase1 = swzf(((wv + 8) * 16 + u) * 32 + q * 8);
    const int wb = u * 32 + q * 8;
    const f4 Z = {0.f, 0.f, 0.f, 0.f};
    float racc = 0.f;

#define ST4F(off_, v0_, v1_, v2_, v3_) {                                     \
    h4 w_; w_.x = (_Float16)(v0_); w_.y = (_Float16)(v1_);                   \
    w_.z = (_Float16)(v2_); w_.w = (_Float16)(v3_);                          \
    *(h4*)&Sst[swzf(off_)] = w_; }

#define ST4(off_, c_) ST4F(off_, (c_).x, (c_).y, (c_).z, (c_).w)

#define MM(sW_)                                                              \
    {                                                                        \
        h8 bf0 = *(const h8*)&Wl[swzw((sW_) + wb)];                          \
        h8 bf1 = *(const h8*)&Wl[swzw((sW_) + 512 + wb)];                    \
        h8 a0 = *(const h8*)&Sst[abase0];                                    \
        h8 a1 = *(const h8*)&Sst[abase1];                                    \
        c00 = __builtin_amdgcn_mfma_f32_16x16x32_f16(a0, bf0, Z, 0, 0, 0);   \
        c01 = __builtin_amdgcn_mfma_f32_16x16x32_f16(a0, bf1, Z, 0, 0, 0);   \
        c10 = __builtin_amdgcn_mfma_f32_16x16x32_f16(a1, bf0, Z, 0, 0, 0);   \
        c11 = __builtin_amdgcn_mfma_f32_16x16x32_f16(a1, bf1, Z, 0, 0, 0);   \
        __syncthreads();                                                     \
    }

// layer-end store: CNOT suffix-xor folded in; 4 slots stay an aligned group,
// values XOR-permuted by e = s2(j0&3), s2(x) = x ^ (x>>1)
#define PST1(off_, e_, v_) {                                                 \
    bool e1_ = ((e_) & 1), e2_ = (((e_) & 2) != 0);                          \
    float b0_ = e1_ ? (v_).y : (v_).x, b1_ = e1_ ? (v_).x : (v_).y;          \
    float b2_ = e1_ ? (v_).w : (v_).z, b3_ = e1_ ? (v_).z : (v_).w;          \
    ST4F(off_, e2_ ? b2_ : b0_, e2_ ? b3_ : b1_,                             \
               e2_ ? b1_ : b3_, e2_ ? b0_ : b2_); }

#define PERMST(tau_, vh0_, vh1_) {                                           \
    int i0_ = u * 256 + (tau_) * 16 + q * 4;                                 \
    int j0_ = sfx(i0_);                                                      \
    int cc_ = j0_ & 3, e_ = cc_ ^ (cc_ >> 1);                                \
    int jb_ = j0_ ^ cc_;                                                     \
    int ob_ = ((jb_ >> 4) << 5) | (jb_ & 12);                                \
    PST1(ob_, e_, vh0_); PST1(ob_ + 16, e_, vh1_); }

#define MEAS(tau_, vh0_, vh1_) {                                             \
    int i0_ = u * 256 + (tau_) * 16 + q * 4;                                 \
    int j0_ = sfx(i0_);                                                      \
    int jl_ = j0_ & 63;                                                      \
    float wh_ = whi[j0_ >> 6];                                               \
    float W0_ = wlo[jl_] + wh_, W1_ = wlo[jl_ ^ 1] + wh_;                    \
    float W2_ = wlo[jl_ ^ 3] + wh_, W3_ = wlo[jl_ ^ 2] + wh_;                \
    racc = fmaf((vh0_).x * (vh0_).x + (vh1_).x * (vh1_).x, W0_, racc);       \
    racc = fmaf((vh0_).y * (vh0_).y + (vh1_).y * (vh1_).y, W1_, racc);       \
    racc = fmaf((vh0_).z * (vh0_).z + (vh1_).z * (vh1_).z, W2_, racc);       \
    racc = fmaf((vh0_).w * (vh0_).w + (vh1_).w * (vh1_).w, W3_, racc); }

#pragma unroll
    for (int l = 0; l < NL; ++l) {
        f4 c00, c01, c10, c11;
        // ---- g=0: wires 8..11 ----
        MM((l * 3 + 0) * 1024)
        {   // D rows (bits 4,5 of i) -> L_1 t-low bits
            int wv3 = wv & 3, wvh = wv >> 2;
            int mf0 = (wv3 | (u << 2) | (wvh << 6)) * 32;
            int mf1 = (wv3 | (u << 2) | ((wvh + 2) << 6)) * 32;
            ST4(mf0 + q * 4, c00); ST4(mf0 + 16 + q * 4, c01);
            ST4(mf1 + q * 4, c10); ST4(mf1 + 16 + q * 4, c11);
            __syncthreads();
        }
        // ---- g=1: wires 4..7 ----
        MM((l * 3 + 1) * 1024)
        {   // D rows (bits 8,9 of i) -> L_2 t-low bits
            int p4 = (wv * 4 + q) & 15;
            int bm = (p4 | (u << 4)) * 32 + (wv >> 2) * 4;
            ST4(bm, c00); ST4(bm + 16, c01);
            ST4(bm + 8, c10); ST4(bm + 24, c11);
            __syncthreads();
        }
        // ---- g=2: wires 0..3 ----
        MM((l * 3 + 2) * 1024)
        if (l < NL - 1) {
            PERMST(wv, c00, c01)
            PERMST(wv + 8, c10, c11)
            __syncthreads();
        } else {
            // measurement: |amp|^2 * wsum(sfx(i)), halves = re/im parts
            MEAS(wv, c00, c01)
            MEAS(wv + 8, c10, c11)
        }
    }

#pragma unroll
    for (int o = 32; o >= 1; o >>= 1) racc += __shfl_xor(racc, o, 64);
    if ((t & 63) == 0) wred[wv] = racc;
    __syncthreads();
    if (t == 0) {
        float r = head_b[0];
#pragma unroll
        for (int i = 0; i < NTHREADS / 64; ++i) r += wred[i];
        out[b] = r;
    }
}

extern "C" void kernel_launch(void* const* d_in, const int* in_sizes, int n_in,
                              void* d_out, int out_size, void* d_ws, size_t ws_size,
                              hipStream_t stream) {
    const float* x = (const float*)d_in[0];
    const float* params = (const float*)d_in[1];
    const float* head_w = (const float*)d_in[2];
    const float* head_b = (const float*)d_in[3];
    float* out = (float*)d_out;
    int B = in_sizes[0] / NQ;

    hipLaunchKernelGGL(qsim_kernel, dim3(B), dim3(NTHREADS), 0, stream,
                       x, params, head_w, head_b, out);
}

// Round 10
// 145.783 us; speedup vs baseline: 1.0992x; 1.0992x over previous
//
#include <hip/hip_runtime.h>
#include <math.h>

#define NQ 12
#define NTH 512
#define NL 3
#define SPB 8   // samples per block; grid = 8192/8 = 1024 = exactly 4 blocks/CU

typedef _Float16 h8 __attribute__((ext_vector_type(8)));
typedef _Float16 h4 __attribute__((ext_vector_type(4)));
typedef float f4 __attribute__((ext_vector_type(4)));

// R10 = bisect round: R7's verified hot-path math VERBATIM (non-interleaved
// layout, R7 W-build, R7 init, R7 PERMST/MEAS) + persistence only (SPB=8
// samples per block, setup amortized). R8/R9's interleave cluster is OUT.

// suffix-xor = CNOT-chain permutation (R4/R7-verified convention)
__device__ __forceinline__ int sfx(int v) {
    v ^= v >> 1; v ^= v >> 2; v ^= v >> 4; v ^= v >> 8;
    return v;
}
// State-buffer swizzle (R6-verified)
__device__ __forceinline__ int swzf(int off) {
    return off ^ (((((off >> 6) ^ (off >> 9)) & 7)) << 3);
}
// W-buffer swizzle (R7-verified)
__device__ __forceinline__ int swzw(int off) {
    return off ^ (((off >> 6) & 7) << 3);
}

// State layouts (R7-verified; state index i, row m, 4-bit tau, reim):
//   off = m*32 + reim*16 + tau
//   L0: tau = i[3:0]  (wires 8..11), m = i[11:4]
//   L1: tau = i[7:4]  (wires 4..7),  m = i[9:8] | i[3:0]<<2 | i[11:10]<<6
//   L2: tau = i[11:8] (wires 0..3),  m = i[7:0]

__global__ void __launch_bounds__(NTH)
qsim_kernel(const float* __restrict__ x,
            const float* __restrict__ params,
            const float* __restrict__ head_w,
            const float* __restrict__ head_b,
            float* __restrict__ out, int Btot) {
    __shared__ __align__(16) _Float16 Sst[8192];   // 16 KB state (256 x 32)
    __shared__ __align__(16) _Float16 Wl[9216];    // 18 KB group matrices
    __shared__ float Gs[36 * 8];                   // fused 2x2 gates
    __shared__ float wlo[64], whi[64];             // R7-verified wsum LUTs
    __shared__ float csx[SPB * NQ], snx[SPB * NQ];
    __shared__ float wred[8];

    const int t = threadIdx.x, blk = blockIdx.x;

    // ---- Phase 1: disjoint lane ranges (R7-verified content) ----
    if (t < 36) {   // fused 2x2 gates G = RY(p2)RZ(p1)RY(p0)
        float p0 = params[t * 3 + 0], p1 = params[t * 3 + 1], p2 = params[t * 3 + 2];
        float c0 = cosf(0.5f * p0), s0 = sinf(0.5f * p0);
        float ch = cosf(0.5f * p1), sh = sinf(0.5f * p1);
        float c2 = cosf(0.5f * p2), s2 = sinf(0.5f * p2);
        float pr = ch, pi = -sh, qr = ch, qi = sh;
        float A = c2 * c0, Bc = s2 * s0, Cc = c2 * s0, D = s2 * c0;
        float* g = &Gs[t * 8];
        g[0] = A * pr - Bc * qr;  g[1] = A * pi - Bc * qi;
        g[2] = -Cc * pr - D * qr; g[3] = -Cc * pi - D * qi;
        g[4] = D * pr + Cc * qr;  g[5] = D * pi + Cc * qi;
        g[6] = -Bc * pr + A * qr; g[7] = -Bc * pi + A * qi;
    }
    if (t >= 128 && t < 192) {       // wlo: bits 0..5 <-> wires 11..6
        int v = t - 128; float s = 0.f;
#pragma unroll
        for (int be = 0; be < 6; ++be)
            s += ((v >> be) & 1) ? -head_w[11 - be] : head_w[11 - be];
        wlo[v] = s;
    }
    if (t >= 192 && t < 256) {       // whi: bits 0..5 <-> wires 5..0
        int v = t - 192; float s = 0.f;
#pragma unroll
        for (int be = 0; be < 6; ++be)
            s += ((v >> be) & 1) ? -head_w[5 - be] : head_w[5 - be];
        whi[v] = s;
    }
    if (t >= 256 && t < 352) {       // RX trig for this block's 8 samples
        int idx = t - 256;
        int s8 = idx / 12, w = idx - s8 * 12;
        int smp = blk * SPB + s8;
        if (smp < Btot) {
            float xv = 0.5f * x[smp * NQ + w];
            csx[idx] = cosf(xv);
            snx[idx] = sinf(xv);
        }
    }
    __syncthreads();

    // ---- Phase 2: W build, VERBATIM R7 (once per block, amortized /SPB) ----
#pragma unroll
    for (int i = 0; i < 18; ++i) {   // 18 x 512 = 9216 elements
        int e = i * 512 + t;
        int s = e >> 10, idx = e & 1023;
        int n = idx >> 5, k = idx & 31;
        int rp = n >> 4, tp = n & 15, rr = k >> 4, tt = k & 15;
        int l = s / 3, g = s - 3 * l;
        float ur = 1.f, ui = 0.f;
#pragma unroll
        for (int jj = 0; jj < 4; ++jj) {
            int wire = 11 - (4 * g + jj);          // bit jj of t <-> wire 11-(4g+jj)
            const float* gp = &Gs[(l * 12 + wire) * 8];
            int rb = (tp >> jj) & 1, cb = (tt >> jj) & 1;
            float gr = gp[(rb * 2 + cb) * 2], gi = gp[(rb * 2 + cb) * 2 + 1];
            float nr = ur * gr - ui * gi;
            float ni = ur * gi + ui * gr;
            ur = nr; ui = ni;
        }
        float val = (rp == 0) ? ((rr == 0) ? ur : -ui)
                              : ((rr == 0) ? ui : ur);
        Wl[swzw(e)] = (_Float16)val;
    }
    __syncthreads();

    // ---- per-lane constants (VERBATIM R7) ----
    const int u = t & 15, q = (t >> 4) & 3, wv = t >> 6;
    const int abase0 = swzf((wv * 16 + u) * 32 + q * 8);
    const int abase1 = swzf(((wv + 8) * 16 + u) * 32 + q * 8);
    const int wb = u * 32 + q * 8;
    const f4 Z = {0.f, 0.f, 0.f, 0.f};

#define ST4F(off_, v0_, v1_, v2_, v3_) {                                     \
    h4 w_; w_.x = (_Float16)(v0_); w_.y = (_Float16)(v1_);                   \
    w_.z = (_Float16)(v2_); w_.w = (_Float16)(v3_);                          \
    *(h4*)&Sst[swzf(off_)] = w_; }

#define ST4(off_, c_) ST4F(off_, (c_).x, (c_).y, (c_).z, (c_).w)

#define MM(sW_) {                                                            \
    h8 bf0 = *(const h8*)&Wl[swzw((sW_) + wb)];                              \
    h8 bf1 = *(const h8*)&Wl[swzw((sW_) + 512 + wb)];                        \
    h8 a0 = *(const h8*)&Sst[abase0];                                        \
    h8 a1 = *(const h8*)&Sst[abase1];                                        \
    c00 = __builtin_amdgcn_mfma_f32_16x16x32_f16(a0, bf0, Z, 0, 0, 0);       \
    c01 = __builtin_amdgcn_mfma_f32_16x16x32_f16(a0, bf1, Z, 0, 0, 0);       \
    c10 = __builtin_amdgcn_mfma_f32_16x16x32_f16(a1, bf0, Z, 0, 0, 0);       \
    c11 = __builtin_amdgcn_mfma_f32_16x16x32_f16(a1, bf1, Z, 0, 0, 0);       \
    __syncthreads(); }

// layer-end store (VERBATIM R7): CNOT suffix-xor; 4 slots stay aligned,
// values XOR-permuted by e = s2(j0&3), s2(x) = x ^ (x>>1)
#define PST1(off_, e_, v_) {                                                 \
    bool e1_ = ((e_) & 1), e2_ = (((e_) & 2) != 0);                          \
    float b0_ = e1_ ? (v_).y : (v_).x, b1_ = e1_ ? (v_).x : (v_).y;          \
    float b2_ = e1_ ? (v_).w : (v_).z, b3_ = e1_ ? (v_).z : (v_).w;          \
    ST4F(off_, e2_ ? b2_ : b0_, e2_ ? b3_ : b1_,                             \
               e2_ ? b1_ : b3_, e2_ ? b0_ : b2_); }

#define PERMST(tau_, vh0_, vh1_) {                                           \
    int i0_ = u * 256 + (tau_) * 16 + q * 4;                                 \
    int j0_ = sfx(i0_);                                                      \
    int cc_ = j0_ & 3, e_ = cc_ ^ (cc_ >> 1);                                \
    int jb_ = j0_ ^ cc_;                                                     \
    int ob_ = ((jb_ >> 4) << 5) | (jb_ & 12);                                \
    PST1(ob_, e_, vh0_); PST1(ob_ + 16, e_, vh1_); }

#define MEAS(tau_, vh0_, vh1_) {                                             \
    int i0_ = u * 256 + (tau_) * 16 + q * 4;                                 \
    int j0_ = sfx(i0_);                                                      \
    int jl_ = j0_ & 63;                                                      \
    float wh_ = whi[j0_ >> 6];                                               \
    float W0_ = wlo[jl_] + wh_, W1_ = wlo[jl_ ^ 1] + wh_;                    \
    float W2_ = wlo[jl_ ^ 3] + wh_, W3_ = wlo[jl_ ^ 2] + wh_;                \
    racc = fmaf(fmaf((vh0_).x, (vh0_).x, (vh1_).x * (vh1_).x), W0_, racc);   \
    racc = fmaf(fmaf((vh0_).y, (vh0_).y, (vh1_).y * (vh1_).y), W1_, racc);   \
    racc = fmaf(fmaf((vh0_).z, (vh0_).z, (vh1_).z * (vh1_).z), W2_, racc);   \
    racc = fmaf(fmaf((vh0_).w, (vh0_).w, (vh1_).w * (vh1_).w), W3_, racc); }

    // ---- sample loop ----
#pragma unroll 1
    for (int s8 = 0; s8 < SPB; ++s8) {
        const int sample = blk * SPB + s8;
        const float* cs = &csx[s8 * NQ];
        const float* sn = &snx[s8 * NQ];
        {   // init: product state (RX encoding), L0 (VERBATIM R7, cs/sn ptrs)
            int m = t & 255, reim = t >> 8;
            float magm = 1.f;
#pragma unroll
            for (int j = 0; j < 8; ++j)       // m bit j = wire 7-j
                magm *= ((m >> j) & 1) ? sn[7 - j] : cs[7 - j];
            float A2[4], B2[4];
#pragma unroll
            for (int v = 0; v < 4; ++v) {     // tau bits 0,1 = wires 11,10; 2,3 = 9,8
                A2[v] = ((v & 1) ? sn[11] : cs[11]) * ((v & 2) ? sn[10] : cs[10]);
                B2[v] = ((v & 1) ? sn[9] : cs[9]) * ((v & 2) ? sn[8] : cs[8]);
            }
            int pm = __popc(m);
            h8 w0, w1;
#pragma unroll
            for (int tau = 0; tau < 16; ++tau) {
                float mag = magm * A2[tau & 3] * B2[tau >> 2];
                int p = (pm + __popc(tau)) & 3;
                bool nz = ((p & 1) == reim);
                bool neg = ((((p >> 1) & 1) ^ reim) != 0);
                float v = nz ? (neg ? -mag : mag) : 0.f;
                if (tau < 8) w0[tau] = (_Float16)v; else w1[tau - 8] = (_Float16)v;
            }
            int off = m * 32 + reim * 16;
            *(h8*)&Sst[swzf(off)] = w0;
            *(h8*)&Sst[swzf(off + 8)] = w1;
        }
        __syncthreads();

        float racc = 0.f;
#pragma unroll
        for (int l = 0; l < NL; ++l) {
            f4 c00, c01, c10, c11;
            // ---- g=0: wires 8..11 ----
            MM((l * 3 + 0) * 1024)
            {   // D rows -> L1 (VERBATIM R7)
                int wv3 = wv & 3, wvh = wv >> 2;
                int mf0 = (wv3 | (u << 2) | (wvh << 6)) * 32;
                int mf1 = (wv3 | (u << 2) | ((wvh + 2) << 6)) * 32;
                ST4(mf0 + q * 4, c00); ST4(mf0 + 16 + q * 4, c01);
                ST4(mf1 + q * 4, c10); ST4(mf1 + 16 + q * 4, c11);
                __syncthreads();
            }
            // ---- g=1: wires 4..7 ----
            MM((l * 3 + 1) * 1024)
            {   // D rows -> L2 (VERBATIM R7)
                int p4 = (wv * 4 + q) & 15;
                int bm = (p4 | (u << 4)) * 32 + (wv >> 2) * 4;
                ST4(bm, c00); ST4(bm + 16, c01);
                ST4(bm + 8, c10); ST4(bm + 24, c11);
                __syncthreads();
            }
            // ---- g=2: wires 0..3 ----
            MM((l * 3 + 2) * 1024)
            if (l < NL - 1) {
                PERMST(wv, c00, c01)
                PERMST(wv + 8, c10, c11)
                __syncthreads();
            } else {
                MEAS(wv, c00, c01)
                MEAS(wv + 8, c10, c11)
            }
        }
#pragma unroll
        for (int o = 32; o >= 1; o >>= 1) racc += __shfl_xor(racc, o, 64);
        if ((t & 63) == 0) wred[wv] = racc;
        __syncthreads();
        if (t == 0 && sample < Btot) {
            float r = head_b[0];
#pragma unroll
            for (int i2 = 0; i2 < 8; ++i2) r += wred[i2];
            out[sample] = r;
        }
    }
}

extern "C" void kernel_launch(void* const* d_in, const int* in_sizes, int n_in,
                              void* d_out, int out_size, void* d_ws, size_t ws_size,
                              hipStream_t stream) {
    const float* x = (const float*)d_in[0];
    const float* params = (const float*)d_in[1];
    const float* head_w = (const float*)d_in[2];
    const float* head_b = (const float*)d_in[3];
    float* out = (float*)d_out;
    int B = in_sizes[0] / NQ;
    int grid = (B + SPB - 1) / SPB;

    hipLaunchKernelGGL(qsim_kernel, dim3(grid), dim3(NTH), 0, stream,
                       x, params, head_w, head_b, out, B);
}

// Round 11
// 127.745 us; speedup vs baseline: 1.2545x; 1.1412x over previous
//
#include <hip/hip_runtime.h>
#include <math.h>

#define NQ 12
#define NTH 512
#define NL 3
#define GRID 768   // 3 blocks/CU x 256 CUs; grid-stride over pairs

typedef _Float16 h8 __attribute__((ext_vector_type(8)));
typedef _Float16 h4 __attribute__((ext_vector_type(4)));
typedef float f4 __attribute__((ext_vector_type(4)));

// R11 = R10's verified math, sample-PAIRED: two states resident (B at +8192
// f16 -> ds offset immediates), W-fragment reads amortized over 2 samples,
// barriers amortized (18+2 per pair vs 20 per sample). DS-pipe analysis R10:
// reads 3456 + stores 1728 + conflicts 1136 cyc/sample ~ 80% of pipe.

// suffix-xor = CNOT-chain permutation (R4/R7/R10-verified)
__device__ __forceinline__ int sfx(int v) {
    v ^= v >> 1; v ^= v >> 2; v ^= v >> 4; v ^= v >> 8;
    return v;
}
// State-buffer swizzle (R6-verified)
__device__ __forceinline__ int swzf(int off) {
    return off ^ (((((off >> 6) ^ (off >> 9)) & 7)) << 3);
}
// W-buffer swizzle (R7-verified)
__device__ __forceinline__ int swzw(int off) {
    return off ^ (((off >> 6) & 7) << 3);
}

// State layouts (R7/R10-verified): off = m*32 + reim*16 + tau
//   L0: tau=i[3:0],  m=i[11:4]
//   L1: tau=i[7:4],  m=i[9:8] | i[3:0]<<2 | i[11:10]<<6
//   L2: tau=i[11:8], m=i[7:0]

__global__ void __launch_bounds__(NTH)
qsim_kernel(const float* __restrict__ x,
            const float* __restrict__ params,
            const float* __restrict__ head_w,
            const float* __restrict__ head_b,
            float* __restrict__ out, int Btot) {
    __shared__ __align__(16) _Float16 Sst[16384];  // 32 KB: states A | B(+8192)
    __shared__ __align__(16) _Float16 Wl[9216];    // 18 KB group matrices
    __shared__ float wlo[64], whi[64];             // R7-verified wsum LUTs
    __shared__ float csx[6 * 24], snx[6 * 24];     // trig for up to 6 pairs
    __shared__ float wred[16];
    float* Gs = (float*)Sst;   // 288-float overlay, dead after W-build

    const int t = threadIdx.x, blk = blockIdx.x;
    const int npairs = (Btot + 1) >> 1;

    // ---- Phase 1: disjoint lane ranges ----
    if (t < 36) {   // fused 2x2 gates G = RY(p2)RZ(p1)RY(p0)  (R4-verified)
        float p0 = params[t * 3 + 0], p1 = params[t * 3 + 1], p2 = params[t * 3 + 2];
        float c0 = cosf(0.5f * p0), s0 = sinf(0.5f * p0);
        float ch = cosf(0.5f * p1), sh = sinf(0.5f * p1);
        float c2 = cosf(0.5f * p2), s2 = sinf(0.5f * p2);
        float pr = ch, pi = -sh, qr = ch, qi = sh;
        float A = c2 * c0, Bc = s2 * s0, Cc = c2 * s0, D = s2 * c0;
        float* g = &Gs[t * 8];
        g[0] = A * pr - Bc * qr;  g[1] = A * pi - Bc * qi;
        g[2] = -Cc * pr - D * qr; g[3] = -Cc * pi - D * qi;
        g[4] = D * pr + Cc * qr;  g[5] = D * pi + Cc * qi;
        g[6] = -Bc * pr + A * qr; g[7] = -Bc * pi + A * qi;
    }
    if (t >= 64 && t < 208) {      // RX trig for this block's <=6 pairs
        int idx = t - 64;
        int pr = idx / 24, w = idx - pr * 24;
        int pairIdx = blk + pr * GRID;
        if (pairIdx < npairs) {
            int smp = pairIdx * 2 + (w >= 12 ? 1 : 0);
            int wire = (w >= 12) ? (w - 12) : w;
            if (smp < Btot) {
                float xv = 0.5f * x[smp * NQ + wire];
                csx[pr * 24 + w] = cosf(xv);
                snx[pr * 24 + w] = sinf(xv);
            }
        }
    }
    if (t >= 256 && t < 320) {     // wlo: bits 0..5 <-> wires 11..6
        int v = t - 256; float s = 0.f;
#pragma unroll
        for (int be = 0; be < 6; ++be)
            s += ((v >> be) & 1) ? -head_w[11 - be] : head_w[11 - be];
        wlo[v] = s;
    }
    if (t >= 320 && t < 384) {     // whi: bits 0..5 <-> wires 5..0
        int v = t - 320; float s = 0.f;
#pragma unroll
        for (int be = 0; be < 6; ++be)
            s += ((v >> be) & 1) ? -head_w[5 - be] : head_w[5 - be];
        whi[v] = s;
    }
    __syncthreads();

    // ---- Phase 2: W build, VERBATIM R10 (once per block) ----
#pragma unroll
    for (int i = 0; i < 18; ++i) {
        int e = i * 512 + t;
        int s = e >> 10, idx = e & 1023;
        int n = idx >> 5, k = idx & 31;
        int rp = n >> 4, tp = n & 15, rr = k >> 4, tt = k & 15;
        int l = s / 3, g = s - 3 * l;
        float ur = 1.f, ui = 0.f;
#pragma unroll
        for (int jj = 0; jj < 4; ++jj) {
            int wire = 11 - (4 * g + jj);
            const float* gp = &Gs[(l * 12 + wire) * 8];
            int rb = (tp >> jj) & 1, cb = (tt >> jj) & 1;
            float gr = gp[(rb * 2 + cb) * 2], gi = gp[(rb * 2 + cb) * 2 + 1];
            float nr = ur * gr - ui * gi;
            float ni = ur * gi + ui * gr;
            ur = nr; ui = ni;
        }
        float val = (rp == 0) ? ((rr == 0) ? ur : -ui)
                              : ((rr == 0) ? ui : ur);
        Wl[swzw(e)] = (_Float16)val;
    }
    __syncthreads();

    // ---- per-lane constants (VERBATIM R10 formulas, hoisted) ----
    const int u = t & 15, q = (t >> 4) & 3, wv = t >> 6;
    const int abase0 = swzf((wv * 16 + u) * 32 + q * 8);
    const int abase1 = swzf(((wv + 8) * 16 + u) * 32 + q * 8);
    const int wbs = swzw(u * 32 + q * 8);   // swzw(sW+wb) == sW + swzw(wb)
    // g0-store offsets (-> L1)
    const int wv3 = wv & 3, wvh = wv >> 2;
    const int mf0 = (wv3 | (u << 2) | (wvh << 6)) * 32;
    const int mf1 = (wv3 | (u << 2) | ((wvh + 2) << 6)) * 32;
    const int s00 = swzf(mf0 + q * 4), s01 = swzf(mf0 + 16 + q * 4);
    const int s10 = swzf(mf1 + q * 4), s11 = swzf(mf1 + 16 + q * 4);
    // g1-store offsets (-> L2)
    const int p4 = (wv * 4 + q) & 15;
    const int bm = (p4 | (u << 4)) * 32 + (wv >> 2) * 4;
    const int b00 = swzf(bm), b01 = swzf(bm + 16), b10 = swzf(bm + 8), b11 = swzf(bm + 24);
    // PERMST constants (layer-end CNOT perm, VERBATIM R10 internals hoisted)
    const int j0a = sfx(u * 256 + wv * 16 + q * 4);
    const int j0b = sfx(u * 256 + (wv + 8) * 16 + q * 4);
    const int cca = j0a & 3, ccb = j0b & 3;
    const int ea = cca ^ (cca >> 1), eb = ccb ^ (ccb >> 1);
    const int jba = j0a ^ cca, jbb = j0b ^ ccb;
    const int obA = ((jba >> 4) << 5) | (jba & 12);
    const int obB = ((jbb >> 4) << 5) | (jbb & 12);
    const int pA0 = swzf(obA), pA1 = swzf(obA + 16);
    const int pB0 = swzf(obB), pB1 = swzf(obB + 16);
    // MEAS weights (loop-invariant, same for both samples of a pair)
    const float wha = whi[j0a >> 6], whb = whi[j0b >> 6];
    const int jla = j0a & 63, jlb = j0b & 63;
    const float W0a = wlo[jla] + wha, W1a = wlo[jla ^ 1] + wha;
    const float W2a = wlo[jla ^ 3] + wha, W3a = wlo[jla ^ 2] + wha;
    const float W0b = wlo[jlb] + whb, W1b = wlo[jlb ^ 1] + whb;
    const float W2b = wlo[jlb ^ 3] + whb, W3b = wlo[jlb ^ 2] + whb;
    const f4 Z = {0.f, 0.f, 0.f, 0.f};

#define STH(off_, c_) { h4 w_;                                               \
    w_.x = (_Float16)(c_).x; w_.y = (_Float16)(c_).y;                        \
    w_.z = (_Float16)(c_).z; w_.w = (_Float16)(c_).w;                        \
    *(h4*)&Sst[off_] = w_; }

// PST1 (VERBATIM R10 value permute), off pre-swizzled, SOFF = 0 or 8192
#define PSTH(off_, SOFF_, e_, v_) {                                          \
    bool e1_ = ((e_) & 1), e2_ = (((e_) & 2) != 0);                          \
    float b0_ = e1_ ? (v_).y : (v_).x, b1_ = e1_ ? (v_).x : (v_).y;          \
    float b2_ = e1_ ? (v_).w : (v_).z, b3_ = e1_ ? (v_).z : (v_).w;          \
    h4 w_;                                                                   \
    w_.x = (_Float16)(e2_ ? b2_ : b0_); w_.y = (_Float16)(e2_ ? b3_ : b1_);  \
    w_.z = (_Float16)(e2_ ? b1_ : b3_); w_.w = (_Float16)(e2_ ? b0_ : b2_);  \
    *(h4*)&Sst[(off_) + (SOFF_)] = w_; }

// read W once, both samples' A-frags, 8 MFMAs, barrier (reads-done)
#define KSTEP(sW_) {                                                         \
    h8 bf0 = *(const h8*)&Wl[(sW_) + wbs];                                   \
    h8 bf1 = *(const h8*)&Wl[(sW_) + 512 + wbs];                             \
    h8 a0A = *(const h8*)&Sst[abase0];                                       \
    h8 a1A = *(const h8*)&Sst[abase1];                                       \
    h8 a0B = *(const h8*)&Sst[abase0 + 8192];                                \
    h8 a1B = *(const h8*)&Sst[abase1 + 8192];                                \
    cA00 = __builtin_amdgcn_mfma_f32_16x16x32_f16(a0A, bf0, Z, 0, 0, 0);     \
    cA01 = __builtin_amdgcn_mfma_f32_16x16x32_f16(a0A, bf1, Z, 0, 0, 0);     \
    cA10 = __builtin_amdgcn_mfma_f32_16x16x32_f16(a1A, bf0, Z, 0, 0, 0);     \
    cA11 = __builtin_amdgcn_mfma_f32_16x16x32_f16(a1A, bf1, Z, 0, 0, 0);     \
    cB00 = __builtin_amdgcn_mfma_f32_16x16x32_f16(a0B, bf0, Z, 0, 0, 0);     \
    cB01 = __builtin_amdgcn_mfma_f32_16x16x32_f16(a0B, bf1, Z, 0, 0, 0);     \
    cB10 = __builtin_amdgcn_mfma_f32_16x16x32_f16(a1B, bf0, Z, 0, 0, 0);     \
    cB11 = __builtin_amdgcn_mfma_f32_16x16x32_f16(a1B, bf1, Z, 0, 0, 0);     \
    __syncthreads(); }

// init one sample's product state (VERBATIM R10 math), SOFF = 0 or 8192
#define INITS(cs_, sn_, SOFF_) {                                             \
    int m_ = t & 255, reim_ = t >> 8;                                        \
    float magm_ = 1.f;                                                       \
    _Pragma("unroll") for (int j_ = 0; j_ < 8; ++j_)                         \
        magm_ *= ((m_ >> j_) & 1) ? (sn_)[7 - j_] : (cs_)[7 - j_];           \
    float A2_[4], B2_[4];                                                    \
    _Pragma("unroll") for (int v_ = 0; v_ < 4; ++v_) {                       \
        A2_[v_] = ((v_ & 1) ? (sn_)[11] : (cs_)[11]) *                       \
                  ((v_ & 2) ? (sn_)[10] : (cs_)[10]);                        \
        B2_[v_] = ((v_ & 1) ? (sn_)[9] : (cs_)[9]) *                         \
                  ((v_ & 2) ? (sn_)[8] : (cs_)[8]);                          \
    }                                                                        \
    int pm_ = __popc(m_);                                                    \
    h8 w0_, w1_;                                                             \
    _Pragma("unroll") for (int tau_ = 0; tau_ < 16; ++tau_) {                \
        float mag_ = magm_ * A2_[tau_ & 3] * B2_[tau_ >> 2];                 \
        int p_ = (pm_ + __popc(tau_)) & 3;                                   \
        bool nz_ = ((p_ & 1) == reim_);                                      \
        bool ng_ = ((((p_ >> 1) & 1) ^ reim_) != 0);                         \
        float v_ = nz_ ? (ng_ ? -mag_ : mag_) : 0.f;                         \
        if (tau_ < 8) w0_[tau_] = (_Float16)v_; else w1_[tau_ - 8] = (_Float16)v_; \
    }                                                                        \
    int off_ = m_ * 32 + reim_ * 16;                                         \
    *(h8*)&Sst[swzf(off_) + (SOFF_)] = w0_;                                  \
    *(h8*)&Sst[swzf(off_ + 8) + (SOFF_)] = w1_; }

    // ---- pair loop (grid-stride over 4096 pairs) ----
#pragma unroll 1
    for (int pr = 0; ; ++pr) {
        const int pairIdx = blk + pr * GRID;
        if (pairIdx >= npairs) break;
        const float* cs0 = &csx[pr * 24];
        const float* sn0 = &snx[pr * 24];
        INITS(cs0, sn0, 0)
        INITS((cs0 + 12), (sn0 + 12), 8192)
        __syncthreads();

        float racc0 = 0.f, racc1 = 0.f;
#pragma unroll
        for (int l = 0; l < NL; ++l) {
            f4 cA00, cA01, cA10, cA11, cB00, cB01, cB10, cB11;
            // ---- g=0: wires 8..11 ----
            KSTEP((l * 3 + 0) * 1024)
            STH(s00, cA00) STH(s01, cA01) STH(s10, cA10) STH(s11, cA11)
            STH(s00 + 8192, cB00) STH(s01 + 8192, cB01)
            STH(s10 + 8192, cB10) STH(s11 + 8192, cB11)
            __syncthreads();
            // ---- g=1: wires 4..7 ----
            KSTEP((l * 3 + 1) * 1024)
            STH(b00, cA00) STH(b01, cA01) STH(b10, cA10) STH(b11, cA11)
            STH(b00 + 8192, cB00) STH(b01 + 8192, cB01)
            STH(b10 + 8192, cB10) STH(b11 + 8192, cB11)
            __syncthreads();
            // ---- g=2: wires 0..3 ----
            KSTEP((l * 3 + 2) * 1024)
            if (l < NL - 1) {   // layer-end CNOT perm (VERBATIM R10 PERMST)
                PSTH(pA0, 0, ea, cA00) PSTH(pA1, 0, ea, cA01)
                PSTH(pB0, 0, eb, cA10) PSTH(pB1, 0, eb, cA11)
                PSTH(pA0, 8192, ea, cB00) PSTH(pA1, 8192, ea, cB01)
                PSTH(pB0, 8192, eb, cB10) PSTH(pB1, 8192, eb, cB11)
                __syncthreads();
            } else {            // measurement (VERBATIM R10 MEAS, weights hoisted)
                racc0 = fmaf(fmaf(cA00.x, cA00.x, cA01.x * cA01.x), W0a, racc0);
                racc0 = fmaf(fmaf(cA00.y, cA00.y, cA01.y * cA01.y), W1a, racc0);
                racc0 = fmaf(fmaf(cA00.z, cA00.z, cA01.z * cA01.z), W2a, racc0);
                racc0 = fmaf(fmaf(cA00.w, cA00.w, cA01.w * cA01.w), W3a, racc0);
                racc0 = fmaf(fmaf(cA10.x, cA10.x, cA11.x * cA11.x), W0b, racc0);
                racc0 = fmaf(fmaf(cA10.y, cA10.y, cA11.y * cA11.y), W1b, racc0);
                racc0 = fmaf(fmaf(cA10.z, cA10.z, cA11.z * cA11.z), W2b, racc0);
                racc0 = fmaf(fmaf(cA10.w, cA10.w, cA11.w * cA11.w), W3b, racc0);
                racc1 = fmaf(fmaf(cB00.x, cB00.x, cB01.x * cB01.x), W0a, racc1);
                racc1 = fmaf(fmaf(cB00.y, cB00.y, cB01.y * cB01.y), W1a, racc1);
                racc1 = fmaf(fmaf(cB00.z, cB00.z, cB01.z * cB01.z), W2a, racc1);
                racc1 = fmaf(fmaf(cB00.w, cB00.w, cB01.w * cB01.w), W3a, racc1);
                racc1 = fmaf(fmaf(cB10.x, cB10.x, cB11.x * cB11.x), W0b, racc1);
                racc1 = fmaf(fmaf(cB10.y, cB10.y, cB11.y * cB11.y), W1b, racc1);
                racc1 = fmaf(fmaf(cB10.z, cB10.z, cB11.z * cB11.z), W2b, racc1);
                racc1 = fmaf(fmaf(cB10.w, cB10.w, cB11.w * cB11.w), W3b, racc1);
            }
        }
#pragma unroll
        for (int o = 32; o >= 1; o >>= 1) {
            racc0 += __shfl_xor(racc0, o, 64);
            racc1 += __shfl_xor(racc1, o, 64);
        }
        if ((t & 63) == 0) { wred[wv] = racc0; wred[8 + wv] = racc1; }
        __syncthreads();
        if (t < 2) {
            int smp = pairIdx * 2 + t;
            if (smp < Btot) {
                float r = head_b[0];
#pragma unroll
                for (int i2 = 0; i2 < 8; ++i2) r += wred[t * 8 + i2];
                out[smp] = r;
            }
        }
    }
}

extern "C" void kernel_launch(void* const* d_in, const int* in_sizes, int n_in,
                              void* d_out, int out_size, void* d_ws, size_t ws_size,
                              hipStream_t stream) {
    const float* x = (const float*)d_in[0];
    const float* params = (const float*)d_in[1];
    const float* head_w = (const float*)d_in[2];
    const float* head_b = (const float*)d_in[3];
    float* out = (float*)d_out;
    int B = in_sizes[0] / NQ;

    hipLaunchKernelGGL(qsim_kernel, dim3(GRID), dim3(NTH), 0, stream,
                       x, params, head_w, head_b, out, B);
}